// Round 4
// baseline (5048.003 us; speedup 1.0000x reference)
//
#include <hip/hip_runtime.h>

// 2-layer GRU, B=512 T=2048 IN=16 H=128 OUT=8.
// 32 WGs x 512 threads (8 waves, 2/SIMD). Wave w owns hidden rows [16w,16w+16)
// of BOTH layers. Transposed MFMA: A=weights, B=h/x, D rows=hidden, cols=batch.
// SOFTWARE-PIPELINED LAYERS: tick t computes h0(t) AND h1(t-1), both from
// h0(t-1) (one LDS read burst) => ONE barrier / step, one latency chain.
// Weights live in registers as f16 A-frags; biases in LDS (broadcast reads);
// h crosses waves via double-buffered LDS with XOR swizzle (conflict-free).
// Barrier = lgkmcnt-only (x prefetch 2-deep + out stores fly across ticks).

typedef unsigned int  uint;
typedef unsigned short ushort;
typedef _Float16 v8h __attribute__((ext_vector_type(8)));
typedef float    v4f __attribute__((ext_vector_type(4)));
typedef uint     v2u __attribute__((ext_vector_type(2)));

#define Tq   2048
#define INq  16
#define Hq   128
#define OUTq 8
#define BW   16

#define MFMA(a,b,c) __builtin_amdgcn_mfma_f32_16x16x32_f16((a),(b),(c),0,0,0)
#define BAR() do { asm volatile("s_waitcnt lgkmcnt(0)" ::: "memory"); \
                   __builtin_amdgcn_s_barrier(); \
                   asm volatile("" ::: "memory"); } while(0)

__device__ __forceinline__ float sigm(float x){
  return __builtin_amdgcn_rcpf(1.0f + __expf(-x));
}
__device__ __forceinline__ float tanh_f(float x){
  return 1.0f - 2.0f*__builtin_amdgcn_rcpf(__expf(2.0f*x) + 1.0f);
}
__device__ __forceinline__ uint packh2(float lo, float hi){
  _Float16 a=(_Float16)lo, b=(_Float16)hi;
  return (uint)__builtin_bit_cast(ushort,a) | ((uint)__builtin_bit_cast(ushort,b)<<16);
}

__global__ __launch_bounds__(512,2) void gru2_kernel(
    const float* __restrict__ x,
    const float* __restrict__ Wih0, const float* __restrict__ Whh0,
    const float* __restrict__ bih0, const float* __restrict__ bhh0,
    const float* __restrict__ Wih1, const float* __restrict__ Whh1,
    const float* __restrict__ bih1, const float* __restrict__ bhh1,
    const float* __restrict__ Wout, const float* __restrict__ bout,
    float* __restrict__ out)
{
  const int tid  = threadIdx.x;
  const int lane = tid & 63;
  const int w    = tid >> 6;      // wave 0..7: hidden slice [16w,16w+16)
  const int nb   = lane & 15;     // batch col (B/D col); weight A-row select
  const int bg   = lane >> 4;     // k-group; D row-group
  const int b0   = blockIdx.x * BW;
  const int hb   = 16*w + nb;     // weight row this lane loads
  const int hb4  = 16*w + bg*4;   // first hidden row of this lane's D regs

  __shared__ __align__(16) _Float16 hA0[2][2048];  // [buf][nb*128+(c^nb)*8+e]
  __shared__ __align__(16) _Float16 hA1[2][2048];
  __shared__ __align__(16) float    bl[1024];      // 8 x 128 bias vectors
  for (int i=tid; i<2048; i+=512){ ((uint*)hA0)[i]=0u; ((uint*)hA1)[i]=0u; }
  for (int i=tid; i<1024; i+=512){
    const int k=i>>7, h=i&127; float v;
    if      (k==0) v = bih0[h]       + bhh0[h];
    else if (k==1) v = bih0[128+h]   + bhh0[128+h];
    else if (k==2) v = bih0[256+h];
    else if (k==3) v = bhh0[256+h];
    else if (k==4) v = bih1[h]       + bhh1[h];
    else if (k==5) v = bih1[128+h]   + bhh1[128+h];
    else if (k==6) v = bih1[256+h];
    else           v = bhh1[256+h];
    bl[i]=v;
  }

  // x prefetch, 2-deep (slot = t&1); per-lane row, waves redundant via L1
  const float* xrow = x + (size_t)(b0+nb)*Tq*INq;
  float4 xqa[2], xqb[2];
  if (bg < 2){
    xqa[0]=*(const float4*)(xrow + 0*INq + bg*8);
    xqb[0]=*(const float4*)(xrow + 0*INq + bg*8 + 4);
    xqa[1]=*(const float4*)(xrow + 1*INq + bg*8);
    xqb[1]=*(const float4*)(xrow + 1*INq + bg*8 + 4);
  }

  // ---------------- weights as f16 A-fragments ----------------
  v8h Fhh0[3][4], Fih1[3][4], Fhh1[3][4], Fx[3], Fo[4];
  #pragma unroll
  for (int g=0; g<3; ++g){
    const int r = g*Hq + hb;
    #pragma unroll
    for (int ks=0; ks<4; ++ks){
      const float* p0 = &Whh0[r*Hq + ks*32 + bg*8];
      const float* p1 = &Wih1[r*Hq + ks*32 + bg*8];
      const float* p2 = &Whh1[r*Hq + ks*32 + bg*8];
      v8h a, b, c;
      #pragma unroll
      for (int e=0;e<8;++e){ a[e]=(_Float16)p0[e]; b[e]=(_Float16)p1[e]; c[e]=(_Float16)p2[e]; }
      Fhh0[g][ks]=a; Fih1[g][ks]=b; Fhh1[g][ks]=c;
    }
    v8h vx;
    #pragma unroll
    for (int e=0;e<8;++e) vx[e]=(_Float16)0.f;
    if (bg < 2){
      const float* p = &Wih0[r*INq + bg*8];
      #pragma unroll
      for (int e=0;e<8;++e) vx[e]=(_Float16)p[e];
    }
    Fx[g]=vx;
  }
  #pragma unroll
  for (int ks=0; ks<4; ++ks){
    v8h v;
    #pragma unroll
    for (int e=0;e<8;++e) v[e]=(_Float16)0.f;
    if (nb < OUTq){
      const float* p = &Wout[nb*Hq + ks*32 + bg*8];
      #pragma unroll
      for (int e=0;e<8;++e) v[e]=(_Float16)p[e];
    }
    Fo[ks]=v;
  }
  v4f bo4 = {0.f,0.f,0.f,0.f};
  if (bg < 2) bo4 = *(const v4f*)(bout + bg*4);

  float h0s[4] = {0,0,0,0};           // h-state: hidden rows hb4+j, batch nb
  float h1s[4] = {0,0,0,0};

  // LDS halfword offsets: read chunk c=ks*4+bg; write own 4 hidden rows
  int rb[4];
  #pragma unroll
  for (int ks=0; ks<4; ++ks) rb[ks] = nb*128 + ((ks*4+bg) ^ nb)*8;
  const int wof = nb*128 + (((2*w + (bg>>1)) ^ nb))*8 + (bg&1)*4;

  __syncthreads();

// tick T_: compute h0(T_) [if DOH0] and h1(T_-1) [if T_>0]; store out(T_-2).
// Reads hA0[PRV]=h0(T_-1), hA1[CUR]=h1(T_-2); writes hA0[CUR], hA1[PRV].
#define TICK(T_, CUR, DOH0) do {                                            \
  const int t_ = (T_);                                                      \
  v4f aR  = *(const v4f*)&bl[0*128+hb4];                                    \
  v4f aZ  = *(const v4f*)&bl[1*128+hb4];                                    \
  v4f aNX = *(const v4f*)&bl[2*128+hb4];                                    \
  v4f aNH = *(const v4f*)&bl[3*128+hb4];                                    \
  v4f cR  = *(const v4f*)&bl[4*128+hb4];                                    \
  v4f cZ  = *(const v4f*)&bl[5*128+hb4];                                    \
  v4f cNX = *(const v4f*)&bl[6*128+hb4];                                    \
  v4f cNH = *(const v4f*)&bl[7*128+hb4];                                    \
  v8h a0[4], a1[4];                                                         \
  _Pragma("unroll")                                                         \
  for (int ks=0; ks<4; ++ks){                                               \
    a0[ks] = *(const v8h*)&hA0[(CUR)^1][rb[ks]];                            \
    a1[ks] = *(const v8h*)&hA1[(CUR)][rb[ks]];                              \
  }                                                                         \
  v8h ax;                                                                   \
  _Pragma("unroll")                                                         \
  for (int e=0;e<8;++e) ax[e]=(_Float16)0.f;                                \
  if (bg < 2){                                                              \
    ax[0]=(_Float16)xqa[CUR].x; ax[1]=(_Float16)xqa[CUR].y;                 \
    ax[2]=(_Float16)xqa[CUR].z; ax[3]=(_Float16)xqa[CUR].w;                 \
    ax[4]=(_Float16)xqb[CUR].x; ax[5]=(_Float16)xqb[CUR].y;                 \
    ax[6]=(_Float16)xqb[CUR].z; ax[7]=(_Float16)xqb[CUR].w;                 \
    int tn = t_ + 2; if (tn > Tq-1) tn = Tq-1;                              \
    xqa[CUR]=*(const float4*)(xrow + tn*INq + bg*8);                        \
    xqb[CUR]=*(const float4*)(xrow + tn*INq + bg*8 + 4);                    \
  }                                                                         \
  if (DOH0){                                                                \
    aR  = MFMA(Fx[0], ax, aR);                                              \
    aZ  = MFMA(Fx[1], ax, aZ);                                              \
    aNX = MFMA(Fx[2], ax, aNX);                                             \
    _Pragma("unroll")                                                       \
    for (int ks=0; ks<4; ++ks){                                             \
      aR  = MFMA(Fhh0[0][ks], a0[ks], aR);                                  \
      aZ  = MFMA(Fhh0[1][ks], a0[ks], aZ);                                  \
      aNH = MFMA(Fhh0[2][ks], a0[ks], aNH);                                 \
    }                                                                       \
  }                                                                         \
  if (t_ > 0){                                                              \
    _Pragma("unroll")                                                       \
    for (int ks=0; ks<4; ++ks){                                             \
      cR  = MFMA(Fih1[0][ks], a0[ks], cR);                                  \
      cZ  = MFMA(Fih1[1][ks], a0[ks], cZ);                                  \
      cNX = MFMA(Fih1[2][ks], a0[ks], cNX);                                 \
      cR  = MFMA(Fhh1[0][ks], a1[ks], cR);                                  \
      cZ  = MFMA(Fhh1[1][ks], a1[ks], cZ);                                  \
      cNH = MFMA(Fhh1[2][ks], a1[ks], cNH);                                 \
    }                                                                       \
  }                                                                         \
  if (DOH0){                                                                \
    float hn0[4];                                                           \
    _Pragma("unroll")                                                       \
    for (int j=0;j<4;++j){                                                  \
      float r = sigm(aR[j]);                                                \
      float z = sigm(aZ[j]);                                                \
      float n = tanh_f(aNX[j] + r*aNH[j]);                                  \
      float h = n + z*(h0s[j]-n);                                           \
      h0s[j]=h; hn0[j]=h;                                                   \
    }                                                                       \
    v2u pk; pk[0]=packh2(hn0[0],hn0[1]); pk[1]=packh2(hn0[2],hn0[3]);       \
    *(v2u*)&hA0[(CUR)][wof] = pk;                                           \
  }                                                                         \
  if (t_ > 0){                                                              \
    if (w == 7){                                                            \
      v4f oac = {0.f,0.f,0.f,0.f};                                          \
      _Pragma("unroll")                                                     \
      for (int ks=0; ks<4; ++ks) oac = MFMA(Fo[ks], a1[ks], oac);           \
      if (t_ >= 2 && bg < 2){                                               \
        float4 o;                                                           \
        o.x=oac[0]+bo4[0]; o.y=oac[1]+bo4[1];                               \
        o.z=oac[2]+bo4[2]; o.w=oac[3]+bo4[3];                               \
        *(float4*)&out[((size_t)(b0+nb)*Tq + (t_-2))*OUTq + bg*4] = o;      \
      }                                                                     \
    }                                                                       \
    float hn1[4];                                                           \
    _Pragma("unroll")                                                       \
    for (int j=0;j<4;++j){                                                  \
      float r = sigm(cR[j]);                                                \
      float z = sigm(cZ[j]);                                                \
      float n = tanh_f(cNX[j] + r*cNH[j]);                                  \
      float h = n + z*(h1s[j]-n);                                           \
      h1s[j]=h; hn1[j]=h;                                                   \
    }                                                                       \
    v2u pk; pk[0]=packh2(hn1[0],hn1[1]); pk[1]=packh2(hn1[2],hn1[3]);       \
    *(v2u*)&hA1[(CUR)^1][wof] = pk;                                         \
  }                                                                         \
  BAR();                                                                    \
} while(0)

  for (int t2=0; t2<Tq; t2+=2){
    TICK(t2,   0, true);
    TICK(t2+1, 1, true);
  }
  TICK(Tq, 0, false);   // final: h1(Tq-1) + out(Tq-2); writes hA1[1]

  // epilogue: out(Tq-1) from h1(Tq-1) in hA1[1]
  if (w == 7){
    v4f oac = {0.f,0.f,0.f,0.f};
    #pragma unroll
    for (int ks=0; ks<4; ++ks){
      v8h a1 = *(const v8h*)&hA1[1][rb[ks]];
      oac = MFMA(Fo[ks], a1, oac);
    }
    if (bg < 2){
      float4 o;
      o.x=oac[0]+bo4[0]; o.y=oac[1]+bo4[1]; o.z=oac[2]+bo4[2]; o.w=oac[3]+bo4[3];
      *(float4*)&out[((size_t)(b0+nb)*Tq + (Tq-1))*OUTq + bg*4] = o;
    }
  }
}

extern "C" void kernel_launch(void* const* d_in, const int* in_sizes, int n_in,
                              void* d_out, int out_size, void* d_ws, size_t ws_size,
                              hipStream_t stream) {
  const float* x    = (const float*)d_in[0];
  const float* Wih0 = (const float*)d_in[1];
  const float* Whh0 = (const float*)d_in[2];
  const float* bih0 = (const float*)d_in[3];
  const float* bhh0 = (const float*)d_in[4];
  const float* Wih1 = (const float*)d_in[5];
  const float* Whh1 = (const float*)d_in[6];
  const float* bih1 = (const float*)d_in[7];
  const float* bhh1 = (const float*)d_in[8];
  const float* Wout = (const float*)d_in[9];
  const float* bo   = (const float*)d_in[10];
  gru2_kernel<<<dim3(32), dim3(512), 0, stream>>>(
      x, Wih0, Whh0, bih0, bhh0, Wih1, Whh1, bih1, bhh1, Wout, bo,
      (float*)d_out);
}

// Round 5
// 3377.703 us; speedup vs baseline: 1.4945x; 1.4945x over previous
//
#include <hip/hip_runtime.h>

// 2-layer GRU, B=512 T=2048 IN=16 H=128 OUT=8.
// 32 WGs x 512 threads (8 waves, 2/SIMD). Wave w owns hidden rows [16w,16w+16)
// of both layers. Transposed MFMA: A=weights, B=h/x, D rows=hidden, cols=batch.
// PIPELINED LAYERS, ONE BARRIER/TICK: tick t computes h0(t) and h1(t-1), both
// from one read of h0(t-1). Register discipline (r4 spilled at ~290 live):
//   - layer-0 accumulators dead before layer-1's live (staggered, not merged)
//   - a1 fragments transient (read per-ks); a0 kept live (16 regs, reused 2x)
//   - x prefetch 1-deep; biases in LDS; oac redundantly on all waves
// Barrier = lgkmcnt-only (x loads + out stores fly across ticks).

typedef unsigned int  uint;
typedef unsigned short ushort;
typedef _Float16 v8h __attribute__((ext_vector_type(8)));
typedef float    v4f __attribute__((ext_vector_type(4)));
typedef uint     v2u __attribute__((ext_vector_type(2)));

#define Tq   2048
#define INq  16
#define Hq   128
#define OUTq 8
#define BW   16

#define MFMA(a,b,c) __builtin_amdgcn_mfma_f32_16x16x32_f16((a),(b),(c),0,0,0)
#define BAR() do { asm volatile("s_waitcnt lgkmcnt(0)" ::: "memory"); \
                   __builtin_amdgcn_s_barrier(); \
                   asm volatile("" ::: "memory"); } while(0)

__device__ __forceinline__ float sigm(float x){
  return __builtin_amdgcn_rcpf(1.0f + __expf(-x));
}
__device__ __forceinline__ float tanh_f(float x){
  return 1.0f - 2.0f*__builtin_amdgcn_rcpf(__expf(2.0f*x) + 1.0f);
}
__device__ __forceinline__ uint packh2(float lo, float hi){
  _Float16 a=(_Float16)lo, b=(_Float16)hi;
  return (uint)__builtin_bit_cast(ushort,a) | ((uint)__builtin_bit_cast(ushort,b)<<16);
}

__global__ __launch_bounds__(512,2) void gru2_kernel(
    const float* __restrict__ x,
    const float* __restrict__ Wih0, const float* __restrict__ Whh0,
    const float* __restrict__ bih0, const float* __restrict__ bhh0,
    const float* __restrict__ Wih1, const float* __restrict__ Whh1,
    const float* __restrict__ bih1, const float* __restrict__ bhh1,
    const float* __restrict__ Wout, const float* __restrict__ bout,
    float* __restrict__ out)
{
  const int tid  = threadIdx.x;
  const int lane = tid & 63;
  const int w    = tid >> 6;      // wave 0..7: hidden slice [16w,16w+16)
  const int nb   = lane & 15;     // batch col (B/D col); weight A-row select
  const int bg   = lane >> 4;     // k-group; D row-group
  const int b0   = blockIdx.x * BW;
  const int hb   = 16*w + nb;     // weight row this lane loads
  const int hb4  = 16*w + bg*4;   // first hidden row of this lane's D regs

  __shared__ __align__(16) _Float16 hA0[2][2048];  // [buf][nb*128+(c^nb)*8+e]
  __shared__ __align__(16) _Float16 hA1[2][2048];
  __shared__ __align__(16) float    bl[1024];      // 8 x 128 bias vectors
  for (int i=tid; i<2048; i+=512){ ((uint*)hA0)[i]=0u; ((uint*)hA1)[i]=0u; }
  for (int i=tid; i<1024; i+=512){
    const int k=i>>7, h=i&127; float v;
    if      (k==0) v = bih0[h]       + bhh0[h];
    else if (k==1) v = bih0[128+h]   + bhh0[128+h];
    else if (k==2) v = bih0[256+h];
    else if (k==3) v = bhh0[256+h];
    else if (k==4) v = bih1[h]       + bhh1[h];
    else if (k==5) v = bih1[128+h]   + bhh1[128+h];
    else if (k==6) v = bih1[256+h];
    else           v = bhh1[256+h];
    bl[i]=v;
  }

  // x prefetch, 1-deep: xfa/xfb hold x(t) at top of tick t
  const float* xrow = x + (size_t)(b0+nb)*Tq*INq;
  float4 xfa, xfb;
  if (bg < 2){
    xfa = *(const float4*)(xrow + 0*INq + bg*8);
    xfb = *(const float4*)(xrow + 0*INq + bg*8 + 4);
  }

  // ---------------- weights as f16 A-fragments ----------------
  v8h Fhh0[3][4], Fih1[3][4], Fhh1[3][4], Fx[3], Fo[4];
  #pragma unroll
  for (int g=0; g<3; ++g){
    const int r = g*Hq + hb;
    #pragma unroll
    for (int ks=0; ks<4; ++ks){
      const float* p0 = &Whh0[r*Hq + ks*32 + bg*8];
      const float* p1 = &Wih1[r*Hq + ks*32 + bg*8];
      const float* p2 = &Whh1[r*Hq + ks*32 + bg*8];
      v8h a, b, c;
      #pragma unroll
      for (int e=0;e<8;++e){ a[e]=(_Float16)p0[e]; b[e]=(_Float16)p1[e]; c[e]=(_Float16)p2[e]; }
      Fhh0[g][ks]=a; Fih1[g][ks]=b; Fhh1[g][ks]=c;
    }
    v8h vx;
    #pragma unroll
    for (int e=0;e<8;++e) vx[e]=(_Float16)0.f;
    if (bg < 2){
      const float* p = &Wih0[r*INq + bg*8];
      #pragma unroll
      for (int e=0;e<8;++e) vx[e]=(_Float16)p[e];
    }
    Fx[g]=vx;
  }
  #pragma unroll
  for (int ks=0; ks<4; ++ks){
    v8h v;
    #pragma unroll
    for (int e=0;e<8;++e) v[e]=(_Float16)0.f;
    if (nb < OUTq){
      const float* p = &Wout[nb*Hq + ks*32 + bg*8];
      #pragma unroll
      for (int e=0;e<8;++e) v[e]=(_Float16)p[e];
    }
    Fo[ks]=v;
  }
  v4f bo4 = {0.f,0.f,0.f,0.f};
  if (bg < 2) bo4 = *(const v4f*)(bout + bg*4);

  float h0s[4] = {0,0,0,0};           // h-state: hidden rows hb4+j, batch nb
  float h1s[4] = {0,0,0,0};

  int rb[4];
  #pragma unroll
  for (int ks=0; ks<4; ++ks) rb[ks] = nb*128 + ((ks*4+bg) ^ nb)*8;
  const int wof = nb*128 + (((2*w + (bg>>1)) ^ nb))*8 + (bg&1)*4;

  __syncthreads();

  // ================= tick 0: layer-0 only =================
  {
    v4f aR  = *(const v4f*)&bl[0*128+hb4];
    v4f aZ  = *(const v4f*)&bl[1*128+hb4];
    v4f aNX = *(const v4f*)&bl[2*128+hb4];
    v4f aNH = *(const v4f*)&bl[3*128+hb4];
    v8h ax;
    #pragma unroll
    for (int e=0;e<8;++e) ax[e]=(_Float16)0.f;
    if (bg < 2){
      ax[0]=(_Float16)xfa.x; ax[1]=(_Float16)xfa.y; ax[2]=(_Float16)xfa.z; ax[3]=(_Float16)xfa.w;
      ax[4]=(_Float16)xfb.x; ax[5]=(_Float16)xfb.y; ax[6]=(_Float16)xfb.z; ax[7]=(_Float16)xfb.w;
      xfa = *(const float4*)(xrow + 1*INq + bg*8);
      xfb = *(const float4*)(xrow + 1*INq + bg*8 + 4);
    }
    aR  = MFMA(Fx[0], ax, aR);
    aZ  = MFMA(Fx[1], ax, aZ);
    aNX = MFMA(Fx[2], ax, aNX);
    // h0(-1)=0 -> hh contributions are zero; skip those MFMAs
    float hn0[4];
    #pragma unroll
    for (int j=0;j<4;++j){
      float r = sigm(aR[j]);
      float z = sigm(aZ[j]);
      float n = tanh_f(aNX[j] + r*aNH[j]);
      float h = n - z*n;                       // h0(-1)=0
      h0s[j]=h; hn0[j]=h;
    }
    v2u pk; pk[0]=packh2(hn0[0],hn0[1]); pk[1]=packh2(hn0[2],hn0[3]);
    *(v2u*)&hA0[0][wof] = pk;
    BAR();
  }

  // ================= main ticks t=1..Tq-1 =================
  for (int t=1; t<Tq; ++t){
    const int cur = t&1, prv = cur^1;

    // ---- reads first: a0 frags (reused by BOTH layers) + layer-0 biases
    v8h a0k[4];
    #pragma unroll
    for (int ks=0; ks<4; ++ks) a0k[ks] = *(const v8h*)&hA0[prv][rb[ks]];
    v4f aR  = *(const v4f*)&bl[0*128+hb4];
    v4f aZ  = *(const v4f*)&bl[1*128+hb4];
    v4f aNX = *(const v4f*)&bl[2*128+hb4];
    v4f aNH = *(const v4f*)&bl[3*128+hb4];

    v8h ax;
    #pragma unroll
    for (int e=0;e<8;++e) ax[e]=(_Float16)0.f;
    if (bg < 2){
      ax[0]=(_Float16)xfa.x; ax[1]=(_Float16)xfa.y; ax[2]=(_Float16)xfa.z; ax[3]=(_Float16)xfa.w;
      ax[4]=(_Float16)xfb.x; ax[5]=(_Float16)xfb.y; ax[6]=(_Float16)xfb.z; ax[7]=(_Float16)xfb.w;
      int tn = t+1; if (tn > Tq-1) tn = Tq-1;
      xfa = *(const float4*)(xrow + tn*INq + bg*8);
      xfb = *(const float4*)(xrow + tn*INq + bg*8 + 4);
    }

    // ---- layer-0 gates
    aR  = MFMA(Fx[0], ax, aR);
    aZ  = MFMA(Fx[1], ax, aZ);
    aNX = MFMA(Fx[2], ax, aNX);
    #pragma unroll
    for (int ks=0; ks<4; ++ks){
      aR  = MFMA(Fhh0[0][ks], a0k[ks], aR);
      aZ  = MFMA(Fhh0[1][ks], a0k[ks], aZ);
      aNH = MFMA(Fhh0[2][ks], a0k[ks], aNH);
    }
    // ---- layer-0 elementwise + write h0(t)   (independent of layer-1 MFMAs;
    //      scheduler interleaves its trans chain with the MFMA issue below)
    float hn0[4];
    #pragma unroll
    for (int j=0;j<4;++j){
      float r = sigm(aR[j]);
      float z = sigm(aZ[j]);
      float n = tanh_f(aNX[j] + r*aNH[j]);
      float h = n + z*(h0s[j]-n);
      h0s[j]=h; hn0[j]=h;
    }
    { v2u pk; pk[0]=packh2(hn0[0],hn0[1]); pk[1]=packh2(hn0[2],hn0[3]);
      *(v2u*)&hA0[cur][wof] = pk; }

    // ---- layer-1 gates (a0k reused; a1 transient per-ks; oac on all waves)
    v4f cR  = *(const v4f*)&bl[4*128+hb4];
    v4f cZ  = *(const v4f*)&bl[5*128+hb4];
    v4f cNX = *(const v4f*)&bl[6*128+hb4];
    v4f cNH = *(const v4f*)&bl[7*128+hb4];
    v4f oac = {0.f,0.f,0.f,0.f};
    #pragma unroll
    for (int ks=0; ks<4; ++ks){
      v8h a1 = *(const v8h*)&hA1[cur][rb[ks]];
      cR  = MFMA(Fih1[0][ks], a0k[ks], cR);
      cZ  = MFMA(Fih1[1][ks], a0k[ks], cZ);
      cNX = MFMA(Fih1[2][ks], a0k[ks], cNX);
      cR  = MFMA(Fhh1[0][ks], a1, cR);
      cZ  = MFMA(Fhh1[1][ks], a1, cZ);
      cNH = MFMA(Fhh1[2][ks], a1, cNH);
      oac = MFMA(Fo[ks],      a1, oac);
    }
    float hn1[4];
    #pragma unroll
    for (int j=0;j<4;++j){
      float r = sigm(cR[j]);
      float z = sigm(cZ[j]);
      float n = tanh_f(cNX[j] + r*cNH[j]);
      float h = n + z*(h1s[j]-n);
      h1s[j]=h; hn1[j]=h;
    }
    { v2u pk; pk[0]=packh2(hn1[0],hn1[1]); pk[1]=packh2(hn1[2],hn1[3]);
      *(v2u*)&hA1[prv][wof] = pk; }

    // out(t-2) store (wave 7; t=1 writes bias-garbage to out(0), overwritten at t=2)
    if (w == 7 && bg < 2){
      int to = t-2; if (to < 0) to = 0;
      float4 o;
      o.x=oac[0]+bo4[0]; o.y=oac[1]+bo4[1]; o.z=oac[2]+bo4[2]; o.w=oac[3]+bo4[3];
      *(float4*)&out[((size_t)(b0+nb)*Tq + to)*OUTq + bg*4] = o;
    }
    BAR();
  }

  // ================= final tick t=Tq: layer-1 only =================
  {
    v8h a0k[4];
    #pragma unroll
    for (int ks=0; ks<4; ++ks) a0k[ks] = *(const v8h*)&hA0[1][rb[ks]];
    v4f cR  = *(const v4f*)&bl[4*128+hb4];
    v4f cZ  = *(const v4f*)&bl[5*128+hb4];
    v4f cNX = *(const v4f*)&bl[6*128+hb4];
    v4f cNH = *(const v4f*)&bl[7*128+hb4];
    v4f oac = {0.f,0.f,0.f,0.f};
    #pragma unroll
    for (int ks=0; ks<4; ++ks){
      v8h a1 = *(const v8h*)&hA1[0][rb[ks]];
      cR  = MFMA(Fih1[0][ks], a0k[ks], cR);
      cZ  = MFMA(Fih1[1][ks], a0k[ks], cZ);
      cNX = MFMA(Fih1[2][ks], a0k[ks], cNX);
      cR  = MFMA(Fhh1[0][ks], a1, cR);
      cZ  = MFMA(Fhh1[1][ks], a1, cZ);
      cNH = MFMA(Fhh1[2][ks], a1, cNH);
      oac = MFMA(Fo[ks],      a1, oac);
    }
    float hn1[4];
    #pragma unroll
    for (int j=0;j<4;++j){
      float r = sigm(cR[j]);
      float z = sigm(cZ[j]);
      float n = tanh_f(cNX[j] + r*cNH[j]);
      float h = n + z*(h1s[j]-n);
      h1s[j]=h; hn1[j]=h;
    }
    { v2u pk; pk[0]=packh2(hn1[0],hn1[1]); pk[1]=packh2(hn1[2],hn1[3]);
      *(v2u*)&hA1[1][wof] = pk; }
    if (w == 7 && bg < 2){
      float4 o;
      o.x=oac[0]+bo4[0]; o.y=oac[1]+bo4[1]; o.z=oac[2]+bo4[2]; o.w=oac[3]+bo4[3];
      *(float4*)&out[((size_t)(b0+nb)*Tq + (Tq-2))*OUTq + bg*4] = o;
    }
    BAR();
  }

  // epilogue: out(Tq-1) from h1(Tq-1) in hA1[1]
  if (w == 7){
    v4f oac = {0.f,0.f,0.f,0.f};
    #pragma unroll
    for (int ks=0; ks<4; ++ks){
      v8h a1 = *(const v8h*)&hA1[1][rb[ks]];
      oac = MFMA(Fo[ks], a1, oac);
    }
    if (bg < 2){
      float4 o;
      o.x=oac[0]+bo4[0]; o.y=oac[1]+bo4[1]; o.z=oac[2]+bo4[2]; o.w=oac[3]+bo4[3];
      *(float4*)&out[((size_t)(b0+nb)*Tq + (Tq-1))*OUTq + bg*4] = o;
    }
  }
}

extern "C" void kernel_launch(void* const* d_in, const int* in_sizes, int n_in,
                              void* d_out, int out_size, void* d_ws, size_t ws_size,
                              hipStream_t stream) {
  const float* x    = (const float*)d_in[0];
  const float* Wih0 = (const float*)d_in[1];
  const float* Whh0 = (const float*)d_in[2];
  const float* bih0 = (const float*)d_in[3];
  const float* bhh0 = (const float*)d_in[4];
  const float* Wih1 = (const float*)d_in[5];
  const float* Whh1 = (const float*)d_in[6];
  const float* bih1 = (const float*)d_in[7];
  const float* bhh1 = (const float*)d_in[8];
  const float* Wout = (const float*)d_in[9];
  const float* bo   = (const float*)d_in[10];
  gru2_kernel<<<dim3(32), dim3(512), 0, stream>>>(
      x, Wih0, Whh0, bih0, bhh0, Wih1, Whh1, bih1, bhh1, Wout, bo,
      (float*)d_out);
}